// Round 4
// baseline (560.309 us; speedup 1.0000x reference)
//
#include <hip/hip_runtime.h>
#include <hip/hip_bf16.h>

#define NE 64
#define HDIM 1024
#define FDIM 2048
#define TDIM 16384

typedef __attribute__((ext_vector_type(8))) short short8;
typedef __attribute__((ext_vector_type(4))) float f32x4;
typedef unsigned short u16;
typedef unsigned int u32;

__device__ __forceinline__ u16 f2bf(float f) {
  return __bfloat16_as_ushort(__float2bfloat16(f));   // v_cvt RNE; pairs fuse to cvt_pk
}
__device__ __forceinline__ u32 pk2(float a, float b) {
  return (u32)f2bf(a) | ((u32)f2bf(b) << 16);
}

// ---- prep: build M-block map (expert, row0, rowend) from tokens_per_expert ----
__global__ void k_prep(const int* __restrict__ tpe, int4* __restrict__ map,
                       int* __restrict__ nblocks) {
  if (threadIdx.x != 0 || blockIdx.x != 0) return;
  int off = 0, nb = 0;
  for (int e = 0; e < NE; ++e) {
    int n = tpe[e];
    for (int r = 0; r < n; r += 128) {
      int re = (r + 128 < n) ? (r + 128) : n;
      map[nb++] = make_int4(e, off + r, off + re, 0);
    }
    off += n;
  }
  *nblocks = nb;
}

// ---- f32 -> bf16 convert, vectorized ----
__global__ void k_conv(const float4* __restrict__ in, uint2* __restrict__ out, int n4) {
  int stride = gridDim.x * blockDim.x;
  for (int i = blockIdx.x * blockDim.x + threadIdx.x; i < n4; i += stride) {
    float4 v = in[i];
    uint2 o;
    o.x = pk2(v.x, v.y);
    o.y = pk2(v.z, v.w);
    out[i] = o;
  }
}

// ---- grouped GEMM: 128x128 tile, BK=32, 4 waves, 16x16x32 bf16 MFMA,
// double-buffered pipelined loop (issue-early / write-late, one barrier per tile).
// A: bf16 [*][K] rows grouped by expert, global_load_lds (linear [128][32] LDS).
// B per expert, f32, converted on the fly into LDS rows padded to 40 u16 (80B,
// =5x16B: keeps b128 alignment, cycles all bank groups):
//   BMODE==1: B [N][K] k-contig  -> 4x float4 loads, uint2 LDS writes
//   BMODE==2: B [K][N] n-contig  -> 8x float2 loads (2 n-cols x 8 k), 2x b128 writes
template<int K, int N, bool GELU, int BMODE>
__global__ __launch_bounds__(256) void k_gemm(
    const u16* __restrict__ A, const float* __restrict__ Bf, void* __restrict__ C,
    const int4* __restrict__ map, const int* __restrict__ nblocks)
{
  if ((int)blockIdx.x >= *nblocks) return;
  const int4 mi = map[blockIdx.x];
  const int e = mi.x, row0 = mi.y, rowend = mi.z;
  const int n0 = blockIdx.y << 7;
  const int NT = K / 32;

  __shared__ u16 sa[2][4096];        // [128][32] linear
  __shared__ u16 sb[2][128 * 40];    // [128 n][40] (32 k + 8 pad)

  const int tid = threadIdx.x;
  const int wid = tid >> 6, lane = tid & 63;
  const int wr = wid >> 1, wc = wid & 1;
  const int fr = lane & 15, fq = lane >> 4;

  f32x4 acc[4][4];
#pragma unroll
  for (int m = 0; m < 4; ++m)
#pragma unroll
    for (int n = 0; n < 4; ++n) acc[m][n] = (f32x4)0.f;

  const float* B = Bf + (size_t)e * ((size_t)N * K);

  // staging state
  float4 v1[4];     // BMODE1 regs
  float2 v2[8];     // BMODE2 regs
  const int np2 = (tid & 63) << 1;   // BMODE2: first of 2 owned n-columns
  const int oct = tid >> 6;          // BMODE2: k-octet

  auto issueA = [&](int t, int buf) {
#pragma unroll
    for (int i = 0; i < 2; ++i) {
      int slot = i * 256 + tid;
      int row = row0 + (slot >> 2);
      row = row < TDIM ? row : TDIM - 1;
      const u16* g = A + (size_t)row * K + t * 32 + (slot & 3) * 8;
      __builtin_amdgcn_global_load_lds(
          (const __attribute__((address_space(1))) u32*)g,
          (__attribute__((address_space(3))) u32*)(&sa[buf][i * 2048 + wid * 512]),
          16, 0, 0);
    }
  };
  auto loadB = [&](int t) {
    if constexpr (BMODE == 1) {
#pragma unroll
      for (int i = 0; i < 4; ++i) {
        int slot = i * 256 + tid;
        v1[i] = *(const float4*)(B + (size_t)(n0 + (slot >> 3)) * K + t * 32 + (slot & 7) * 4);
      }
    } else {
      const float* src = B + (size_t)(t * 32 + oct * 8) * N + n0 + np2;
#pragma unroll
      for (int i = 0; i < 8; ++i) v2[i] = *(const float2*)(src + (size_t)i * N);
    }
  };
  auto writeB = [&](int buf) {
    if constexpr (BMODE == 1) {
#pragma unroll
      for (int i = 0; i < 4; ++i) {
        int slot = i * 256 + tid;
        uint2 o;
        o.x = pk2(v1[i].x, v1[i].y);
        o.y = pk2(v1[i].z, v1[i].w);
        *(uint2*)(&sb[buf][(slot >> 3) * 40 + (slot & 7) * 4]) = o;
      }
    } else {
      uint4 c0, c1;
      c0.x = pk2(v2[0].x, v2[1].x); c0.y = pk2(v2[2].x, v2[3].x);
      c0.z = pk2(v2[4].x, v2[5].x); c0.w = pk2(v2[6].x, v2[7].x);
      c1.x = pk2(v2[0].y, v2[1].y); c1.y = pk2(v2[2].y, v2[3].y);
      c1.z = pk2(v2[4].y, v2[5].y); c1.w = pk2(v2[6].y, v2[7].y);
      *(uint4*)(&sb[buf][np2 * 40 + oct * 8]) = c0;          // byte np2*80+oct*16
      *(uint4*)(&sb[buf][(np2 + 1) * 40 + oct * 8]) = c1;
    }
  };

  // prologue: tile 0 into buffer 0
  issueA(0, 0);
  loadB(0);
  writeB(0);
  __syncthreads();

  for (int t = 0; t < NT; ++t) {
    const int cur = t & 1, nxt = cur ^ 1;
    if (t + 1 < NT) {
      issueA(t + 1, nxt);     // async global->LDS, drains at end-of-iter barrier
      loadB(t + 1);           // global->reg, latency hidden under MFMA
    }
    short8 av[4], bv[4];
#pragma unroll
    for (int m = 0; m < 4; ++m)
      av[m] = *(const short8*)(&sa[cur][(wr * 64 + m * 16 + fr) * 32 + fq * 8]);
#pragma unroll
    for (int n = 0; n < 4; ++n)
      bv[n] = *(const short8*)(&sb[cur][(wc * 64 + n * 16 + fr) * 40 + fq * 8]);
#pragma unroll
    for (int m = 0; m < 4; ++m)
#pragma unroll
      for (int n = 0; n < 4; ++n)
        acc[m][n] = __builtin_amdgcn_mfma_f32_16x16x32_bf16(av[m], bv[n], acc[m][n], 0, 0, 0);
    if (t + 1 < NT) writeB(nxt);   // cvt+ds_write into other buffer (no reader until next iter)
    __syncthreads();
  }

  // epilogue: C/D layout row=(lane>>4)*4+j, col=lane&15 (m89-verified)
#pragma unroll
  for (int m = 0; m < 4; ++m) {
    const int rb = row0 + wr * 64 + m * 16 + fq * 4;
#pragma unroll
    for (int n = 0; n < 4; ++n) {
      const int col = n0 + wc * 64 + n * 16 + fr;
#pragma unroll
      for (int j = 0; j < 4; ++j) {
        int r = rb + j;
        if (r < rowend) {
          float vv = acc[m][n][j];
          if constexpr (GELU) {
            vv = 0.5f * vv * (1.f + erff(vv * 0.70710678118654752f));
            ((u16*)C)[(size_t)r * N + col] = f2bf(vv);
          } else {
            ((float*)C)[(size_t)r * N + col] = vv;
          }
        }
      }
    }
  }
}

extern "C" void kernel_launch(void* const* d_in, const int* in_sizes, int n_in,
                              void* d_out, int out_size, void* d_ws, size_t ws_size,
                              hipStream_t stream) {
  const float* x  = (const float*)d_in[0];
  const float* w1 = (const float*)d_in[1];
  const float* w2 = (const float*)d_in[2];
  const int*  tpe = (const int*)d_in[3];

  char* ws = (char*)d_ws;
  int4* map     = (int4*)ws;                       // up to 192 entries
  int*  nblocks = (int*)(ws + 4096);
  u16*  xb      = (u16*)(ws + 8192);               // T*H bf16 = 32MB
  u16*  hb      = xb + (size_t)TDIM * HDIM;        // T*F bf16 = 64MB
  // total ws requirement ~96MB

  k_prep<<<1, 64, 0, stream>>>(tpe, map, nblocks);
  k_conv<<<2048, 256, 0, stream>>>((const float4*)x, (uint2*)xb, (TDIM * HDIM) / 4);
  // GEMM1: h = gelu(x @ w1^T)   A=[T][1024] bf16, B=w1 f32 [F][H] = [N][K]
  k_gemm<HDIM, FDIM, true,  1><<<dim3(192, FDIM / 128), 256, 0, stream>>>(
      xb, w1, (void*)hb, map, nblocks);
  // GEMM2: out = h @ w2         A=[T][2048] bf16, B=w2 f32 [F][H] = [K][N]
  k_gemm<FDIM, HDIM, false, 2><<<dim3(192, HDIM / 128), 256, 0, stream>>>(
      hb, w2, d_out, map, nblocks);
}

// Round 5
// 554.993 us; speedup vs baseline: 1.0096x; 1.0096x over previous
//
#include <hip/hip_runtime.h>
#include <hip/hip_bf16.h>

#define NE 64
#define HDIM 1024
#define FDIM 2048
#define TDIM 16384

typedef __attribute__((ext_vector_type(8))) short short8;
typedef __attribute__((ext_vector_type(4))) float f32x4;
typedef unsigned short u16;
typedef unsigned int u32;

struct IC0 { static constexpr int v = 0; };
struct IC1 { static constexpr int v = 1; };

__device__ __forceinline__ u16 f2bf(float f) {
  return __bfloat16_as_ushort(__float2bfloat16(f));
}
__device__ __forceinline__ u32 pk2(float a, float b) {
  return (u32)f2bf(a) | ((u32)f2bf(b) << 16);
}
template<int N> __device__ __forceinline__ void waitv() {
  if constexpr (N == 4)       asm volatile("s_waitcnt vmcnt(4)" ::: "memory");
  else if constexpr (N == 6)  asm volatile("s_waitcnt vmcnt(6)" ::: "memory");
  else if constexpr (N == 8)  asm volatile("s_waitcnt vmcnt(8)" ::: "memory");
  else if constexpr (N == 10) asm volatile("s_waitcnt vmcnt(10)" ::: "memory");
}
__device__ __forceinline__ void waitl() {
  asm volatile("s_waitcnt lgkmcnt(0)" ::: "memory");
}

// ---- prep: build M-block map (expert, row0, rowend) ----
__global__ void k_prep(const int* __restrict__ tpe, int4* __restrict__ map,
                       int* __restrict__ nblocks) {
  if (threadIdx.x != 0 || blockIdx.x != 0) return;
  int off = 0, nb = 0;
  for (int e = 0; e < NE; ++e) {
    int n = tpe[e];
    for (int r = 0; r < n; r += 128) {
      int re = (r + 128 < n) ? (r + 128) : n;
      map[nb++] = make_int4(e, off + r, off + re, 0);
    }
    off += n;
  }
  *nblocks = nb;
}

// ---- f32 -> bf16 convert ----
__global__ void k_conv(const float4* __restrict__ in, uint2* __restrict__ out, int n4) {
  int stride = gridDim.x * blockDim.x;
  for (int i = blockIdx.x * blockDim.x + threadIdx.x; i < n4; i += stride) {
    float4 v = in[i];
    uint2 o;
    o.x = pk2(v.x, v.y);
    o.y = pk2(v.z, v.w);
    out[i] = o;
  }
}

// ---- grouped GEMM: 128x128 tile, BK=32, 4 waves, deep pipeline with raw
// s_barrier + counted vmcnt (loads stay in flight across barriers).
// Flight depths: A (gload_lds, LDS double-buffered) = 2 iters; B (f32->reg,
// ping-pong reg sets, cvt+ds_write into single LDS buf) = 2 iters.
// Steady in-flight at iter top: A(t) 2, B(t+1) LB, A(t+1) 2, B(t+2) LB
//   -> s_waitcnt vmcnt(2+LB) drains exactly A(t)+B(t+1).
template<int K, int N, bool GELU, int BMODE>
__global__ __launch_bounds__(256) void k_gemm(
    const u16* __restrict__ A, const float* __restrict__ Bf, void* __restrict__ C,
    const int4* __restrict__ map, const int* __restrict__ nblocks)
{
  if ((int)blockIdx.x >= *nblocks) return;
  const int4 mi = map[blockIdx.x];
  const int e = mi.x, row0 = mi.y, rowend = mi.z;
  const int n0 = blockIdx.y << 7;
  const int NT = K / 32;                      // 32 or 64, always even
  constexpr int LB = (BMODE == 1) ? 4 : 8;    // B vmem ops per iter per thread

  __shared__ u16 sa[2][4096];      // A [128][32] linear, double-buffered
  __shared__ u16 sb[128 * 40];     // B [128 n][40] (32 k + 8 pad), single

  const int tid = threadIdx.x;
  const int wid = tid >> 6, lane = tid & 63;
  const int wr = wid >> 1, wc = wid & 1;
  const int fr = lane & 15, fq = lane >> 4;

  f32x4 acc[4][4];
#pragma unroll
  for (int m = 0; m < 4; ++m)
#pragma unroll
    for (int n = 0; n < 4; ++n) acc[m][n] = (f32x4)0.f;

  const float* B = Bf + (size_t)e * ((size_t)N * K);

  float4 rb1[2][4];                // BMODE1 ping-pong reg sets
  float2 rb2[2][8];                // BMODE2 ping-pong reg sets
  const int np2 = (tid & 63) << 1; // BMODE2: first of 2 owned n-columns
  const int oct = tid >> 6;        // BMODE2: k-octet

  auto issueA = [&](int t) {
    const int buf = t & 1;
#pragma unroll
    for (int i = 0; i < 2; ++i) {
      int slot = i * 256 + tid;
      int row = row0 + (slot >> 2);
      row = row < TDIM ? row : TDIM - 1;
      const u16* g = A + (size_t)row * K + t * 32 + (slot & 3) * 8;
      __builtin_amdgcn_global_load_lds(
          (const __attribute__((address_space(1))) u32*)g,
          (__attribute__((address_space(3))) u32*)(&sa[buf][i * 2048 + wid * 512]),
          16, 0, 0);
    }
  };
  auto loadB = [&](int t, auto ic) {
    constexpr int S = decltype(ic)::v;
    if constexpr (BMODE == 1) {
#pragma unroll
      for (int i = 0; i < 4; ++i) {
        int slot = i * 256 + tid;
        rb1[S][i] = *(const float4*)(B + (size_t)(n0 + (slot >> 3)) * K + t * 32 + (slot & 7) * 4);
      }
    } else {
      const float* src = B + (size_t)(t * 32 + oct * 8) * N + n0 + np2;
#pragma unroll
      for (int i = 0; i < 8; ++i) rb2[S][i] = *(const float2*)(src + (size_t)i * N);
    }
  };
  auto writeB = [&](auto ic) {
    constexpr int S = decltype(ic)::v;
    if constexpr (BMODE == 1) {
#pragma unroll
      for (int i = 0; i < 4; ++i) {
        int slot = i * 256 + tid;
        uint2 o;
        o.x = pk2(rb1[S][i].x, rb1[S][i].y);
        o.y = pk2(rb1[S][i].z, rb1[S][i].w);
        *(uint2*)(&sb[(slot >> 3) * 40 + (slot & 7) * 4]) = o;
      }
    } else {
      uint4 c0, c1;
      c0.x = pk2(rb2[S][0].x, rb2[S][1].x); c0.y = pk2(rb2[S][2].x, rb2[S][3].x);
      c0.z = pk2(rb2[S][4].x, rb2[S][5].x); c0.w = pk2(rb2[S][6].x, rb2[S][7].x);
      c1.x = pk2(rb2[S][0].y, rb2[S][1].y); c1.y = pk2(rb2[S][2].y, rb2[S][3].y);
      c1.z = pk2(rb2[S][4].y, rb2[S][5].y); c1.w = pk2(rb2[S][6].y, rb2[S][7].y);
      *(uint4*)(&sb[np2 * 40 + oct * 8]) = c0;
      *(uint4*)(&sb[(np2 + 1) * 40 + oct * 8]) = c1;
    }
  };

  auto body = [&](int t, auto icCur) {
    waitv<2 + LB>();     // A(t) landed in sa[t&1]; B(t+1) regs complete
    waitl();             // own ds_writes from prev iter drained
    __builtin_amdgcn_s_barrier();          // R: tiles stable for all waves
    const int cur = t & 1;
    short8 av[4], bv[4];
#pragma unroll
    for (int m = 0; m < 4; ++m)
      av[m] = *(const short8*)(&sa[cur][(wr * 64 + m * 16 + fr) * 32 + fq * 8]);
#pragma unroll
    for (int n = 0; n < 4; ++n)
      bv[n] = *(const short8*)(&sb[(wc * 64 + n * 16 + fr) * 40 + fq * 8]);
    waitl();
    __builtin_amdgcn_sched_barrier(0);     // frags truly in regs (rule 18)
    __builtin_amdgcn_s_barrier();          // W: all waves done reading
    if (t + 2 < NT) issueA(t + 2);         // -> sa[t&1], 2-iter flight
    if (t + 1 < NT) writeB(icCur);         // cvt + ds_write into sb
    if (t + 3 < NT) loadB(t + 3, icCur);   // refill same reg set, 2-iter flight
    __builtin_amdgcn_sched_barrier(0);     // pin staging before MFMA
#pragma unroll
    for (int m = 0; m < 4; ++m)
#pragma unroll
      for (int n = 0; n < 4; ++n)
        acc[m][n] = __builtin_amdgcn_mfma_f32_16x16x32_bf16(av[m], bv[n], acc[m][n], 0, 0, 0);
  };

  // prologue — produces steady-state in-flight ages exactly
  issueA(0);            // sa[0]
  loadB(0, IC0{});
  loadB(1, IC1{});
  waitv<LB>();          // drains A(0)+B(0); B(1) stays in flight
  writeB(IC0{});        // sb <- B(0)
  issueA(1);            // sa[1]
  loadB(2, IC0{});
  for (int t = 0; t < NT; t += 2) {
    body(t, IC1{});     // consumes B(t+1) from set1, refills set1 with B(t+3)
    body(t + 1, IC0{});
  }

  // epilogue: C/D layout row=(lane>>4)*4+j, col=lane&15
#pragma unroll
  for (int m = 0; m < 4; ++m) {
    const int rb = row0 + wr * 64 + m * 16 + fq * 4;
#pragma unroll
    for (int n = 0; n < 4; ++n) {
      const int col = n0 + wc * 64 + n * 16 + fr;
#pragma unroll
      for (int j = 0; j < 4; ++j) {
        int r = rb + j;
        if (r < rowend) {
          float vv = acc[m][n][j];
          if constexpr (GELU) {
            vv = 0.5f * vv * (1.f + erff(vv * 0.70710678118654752f));
            ((u16*)C)[(size_t)r * N + col] = f2bf(vv);
          } else {
            ((float*)C)[(size_t)r * N + col] = vv;
          }
        }
      }
    }
  }
}

extern "C" void kernel_launch(void* const* d_in, const int* in_sizes, int n_in,
                              void* d_out, int out_size, void* d_ws, size_t ws_size,
                              hipStream_t stream) {
  const float* x  = (const float*)d_in[0];
  const float* w1 = (const float*)d_in[1];
  const float* w2 = (const float*)d_in[2];
  const int*  tpe = (const int*)d_in[3];

  char* ws = (char*)d_ws;
  int4* map     = (int4*)ws;
  int*  nblocks = (int*)(ws + 4096);
  u16*  xb      = (u16*)(ws + 8192);               // T*H bf16 = 32MB
  u16*  hb      = xb + (size_t)TDIM * HDIM;        // T*F bf16 = 64MB

  k_prep<<<1, 64, 0, stream>>>(tpe, map, nblocks);
  k_conv<<<2048, 256, 0, stream>>>((const float4*)x, (uint2*)xb, (TDIM * HDIM) / 4);
  // GEMM1: h = gelu(x @ w1^T)   B=w1 f32 [F][H] = [N][K]
  k_gemm<HDIM, FDIM, true,  1><<<dim3(192, FDIM / 128), 256, 0, stream>>>(
      xb, w1, (void*)hb, map, nblocks);
  // GEMM2: out = h @ w2         B=w2 f32 [F][H] = [K][N]
  k_gemm<FDIM, HDIM, false, 2><<<dim3(192, HDIM / 128), 256, 0, stream>>>(
      hb, w2, d_out, map, nblocks);
}

// Round 6
// 540.543 us; speedup vs baseline: 1.0366x; 1.0267x over previous
//
#include <hip/hip_runtime.h>
#include <hip/hip_bf16.h>

#define NE 64
#define HDIM 1024
#define FDIM 2048
#define TDIM 16384

typedef __attribute__((ext_vector_type(8))) short short8;
typedef __attribute__((ext_vector_type(4))) float f32x4;
typedef unsigned short u16;
typedef unsigned int u32;

struct IC0 { static constexpr int v = 0; };
struct IC1 { static constexpr int v = 1; };

__device__ __forceinline__ u16 f2bf(float f) {
  return __bfloat16_as_ushort(__float2bfloat16(f));
}
__device__ __forceinline__ u32 pk2(float a, float b) {
  return (u32)f2bf(a) | ((u32)f2bf(b) << 16);
}
template<int N> __device__ __forceinline__ void waitv() {
  if constexpr (N == 2)       asm volatile("s_waitcnt vmcnt(2)" ::: "memory");
  else if constexpr (N == 4)  asm volatile("s_waitcnt vmcnt(4)" ::: "memory");
  else if constexpr (N == 8)  asm volatile("s_waitcnt vmcnt(8)" ::: "memory");
  else if constexpr (N == 10) asm volatile("s_waitcnt vmcnt(10)" ::: "memory");
}
__device__ __forceinline__ void waitl() {
  asm volatile("s_waitcnt lgkmcnt(0)" ::: "memory");
}

// ---- prep: build M-block map (expert, row0, rowend), BM=256 ----
__global__ void k_prep(const int* __restrict__ tpe, int4* __restrict__ map,
                       int* __restrict__ nblocks) {
  if (threadIdx.x != 0 || blockIdx.x != 0) return;
  int off = 0, nb = 0;
  for (int e = 0; e < NE; ++e) {
    int n = tpe[e];
    for (int r = 0; r < n; r += 256) {
      int re = (r + 256 < n) ? (r + 256) : n;
      map[nb++] = make_int4(e, off + r, off + re, 0);
    }
    off += n;
  }
  *nblocks = nb;
}

// ---- f32 -> bf16 convert ----
__global__ void k_conv(const float4* __restrict__ in, uint2* __restrict__ out, int n4) {
  int stride = gridDim.x * blockDim.x;
  for (int i = blockIdx.x * blockDim.x + threadIdx.x; i < n4; i += stride) {
    float4 v = in[i];
    uint2 o;
    o.x = pk2(v.x, v.y);
    o.y = pk2(v.z, v.w);
    out[i] = o;
  }
}

// ---- grouped GEMM: 256x128 tile, BK=32, 512 threads (8 waves of 64x64),
// 1-D grid with n-inner ordering (consecutive blocks share the A-tile -> L2/L3
// reuse; expert's 2nd M-block is NY bids later -> same XCD -> w-tile L2 hit).
// Deep pipeline: raw s_barrier + counted vmcnt, A gload_lds 2-iter flight
// (LDS dbuf), B f32->reg 2-iter flight (ping-pong reg sets), cvt+ds_write
// into single B buf. Steady top-of-iter: vmcnt(2+LB) drains A(t)+B(t+1).
//   BMODE==1: B [N][K] k-contig  -> 2x float4/thread, uint2 LDS writes
//   BMODE==2: B [K][N] n-contig  -> 8x f32/thread (1 n-col x 8 k), 1x b128 write
template<int K, int N, bool GELU, int BMODE, int NY>
__global__ __launch_bounds__(512) void k_gemm(
    const u16* __restrict__ A, const float* __restrict__ Bf, void* __restrict__ C,
    const int4* __restrict__ map, const int* __restrict__ nblocks)
{
  const int mblk = (int)blockIdx.x / NY;
  const int nblk = (int)blockIdx.x % NY;
  if (mblk >= *nblocks) return;
  const int4 mi = map[mblk];
  const int e = mi.x, row0 = mi.y, rowend = mi.z;
  const int n0 = nblk << 7;
  const int NT = K / 32;                      // 32 or 64, always even
  constexpr int LB = (BMODE == 1) ? 2 : 8;    // B vmem ops per iter per thread

  __shared__ __align__(16) u16 sa[2][8192];   // A [256][32] linear, double-buffered
  __shared__ __align__(16) u16 sb[128 * 40];  // B [128 n][40] (32 k + 8 pad)

  const int tid = threadIdx.x;
  const int wid = tid >> 6, lane = tid & 63;
  const int wr = wid >> 1, wc = wid & 1;      // 4 row-quads x 2 col-halves
  const int fr = lane & 15, fq = lane >> 4;

  f32x4 acc[4][4];
#pragma unroll
  for (int m = 0; m < 4; ++m)
#pragma unroll
    for (int n = 0; n < 4; ++n) acc[m][n] = (f32x4)0.f;

  const float* B = Bf + (size_t)e * ((size_t)N * K);

  float4 rb1[2][2];                 // BMODE1 ping-pong reg sets
  float  rb2[2][8];                 // BMODE2 ping-pong reg sets
  const int bn  = tid & 127;        // BMODE2: owned n-column
  const int oct = tid >> 7;         // BMODE2: k-octet

  auto issueA = [&](int t) {
    const int buf = t & 1;
#pragma unroll
    for (int i = 0; i < 2; ++i) {
      int slot = i * 512 + tid;                 // [0,1024): row=slot>>2, 16B col=slot&3
      int row = row0 + (slot >> 2);
      row = row < TDIM ? row : TDIM - 1;
      const u16* g = A + (size_t)row * K + t * 32 + (slot & 3) * 8;
      __builtin_amdgcn_global_load_lds(
          (const __attribute__((address_space(1))) u32*)g,
          (__attribute__((address_space(3))) u32*)(&sa[buf][i * 4096 + wid * 512]),
          16, 0, 0);
    }
  };
  auto loadB = [&](int t, auto ic) {
    constexpr int S = decltype(ic)::v;
    if constexpr (BMODE == 1) {
#pragma unroll
      for (int i = 0; i < 2; ++i) {
        int slot = i * 512 + tid;               // n=slot>>3, k16=slot&7
        rb1[S][i] = *(const float4*)(B + (size_t)(n0 + (slot >> 3)) * K + t * 32 + (slot & 7) * 4);
      }
    } else {
      const float* src = B + (size_t)(t * 32 + oct * 8) * N + n0 + bn;
#pragma unroll
      for (int i = 0; i < 8; ++i) rb2[S][i] = src[(size_t)i * N];
    }
  };
  auto writeB = [&](auto ic) {
    constexpr int S = decltype(ic)::v;
    if constexpr (BMODE == 1) {
#pragma unroll
      for (int i = 0; i < 2; ++i) {
        int slot = i * 512 + tid;
        uint2 o;
        o.x = pk2(rb1[S][i].x, rb1[S][i].y);
        o.y = pk2(rb1[S][i].z, rb1[S][i].w);
        *(uint2*)(&sb[(slot >> 3) * 40 + (slot & 7) * 4]) = o;
      }
    } else {
      uint4 c;
      c.x = pk2(rb2[S][0], rb2[S][1]); c.y = pk2(rb2[S][2], rb2[S][3]);
      c.z = pk2(rb2[S][4], rb2[S][5]); c.w = pk2(rb2[S][6], rb2[S][7]);
      *(uint4*)(&sb[bn * 40 + oct * 8]) = c;    // byte bn*80 + oct*16 (80=5x16: aligned)
    }
  };

  auto body = [&](int t, auto icCur) {
    waitv<2 + LB>();     // A(t) landed in sa[t&1]; B(t+1) regs complete
    waitl();             // own ds_writes from prev iter drained
    __builtin_amdgcn_s_barrier();          // R: tiles stable for all waves
    const int cur = t & 1;
    short8 av[4], bv[4];
#pragma unroll
    for (int m = 0; m < 4; ++m)
      av[m] = *(const short8*)(&sa[cur][(wr * 64 + m * 16 + fr) * 32 + fq * 8]);
#pragma unroll
    for (int n = 0; n < 4; ++n)
      bv[n] = *(const short8*)(&sb[(wc * 64 + n * 16 + fr) * 40 + fq * 8]);
    waitl();
    __builtin_amdgcn_sched_barrier(0);     // frags truly in regs (rule 18)
    __builtin_amdgcn_s_barrier();          // W: all waves done reading
    if (t + 2 < NT) issueA(t + 2);         // -> sa[t&1], 2-iter flight
    if (t + 1 < NT) writeB(icCur);         // cvt + ds_write into sb
    if (t + 3 < NT) loadB(t + 3, icCur);   // refill same reg set, 2-iter flight
    __builtin_amdgcn_sched_barrier(0);     // pin staging before MFMA
#pragma unroll
    for (int m = 0; m < 4; ++m)
#pragma unroll
      for (int n = 0; n < 4; ++n)
        acc[m][n] = __builtin_amdgcn_mfma_f32_16x16x32_bf16(av[m], bv[n], acc[m][n], 0, 0, 0);
  };

  // prologue — reproduces steady-state in-flight ages exactly
  issueA(0);            // sa[0]
  loadB(0, IC0{});
  loadB(1, IC1{});
  waitv<LB>();          // drains A(0)+B(0); B(1) stays in flight
  writeB(IC0{});        // sb <- B(0)
  issueA(1);            // sa[1]
  loadB(2, IC0{});
  for (int t = 0; t < NT; t += 2) {
    body(t, IC1{});     // consumes B(t+1) from set1, refills set1 with B(t+3)
    body(t + 1, IC0{});
  }

  // epilogue: C/D layout row=(lane>>4)*4+j, col=lane&15
#pragma unroll
  for (int m = 0; m < 4; ++m) {
    const int rb = row0 + wr * 64 + m * 16 + fq * 4;
#pragma unroll
    for (int n = 0; n < 4; ++n) {
      const int col = n0 + wc * 64 + n * 16 + fr;
#pragma unroll
      for (int j = 0; j < 4; ++j) {
        int r = rb + j;
        if (r < rowend) {
          float vv = acc[m][n][j];
          if constexpr (GELU) {
            vv = 0.5f * vv * (1.f + erff(vv * 0.70710678118654752f));
            ((u16*)C)[(size_t)r * N + col] = f2bf(vv);
          } else {
            ((float*)C)[(size_t)r * N + col] = vv;
          }
        }
      }
    }
  }
}

extern "C" void kernel_launch(void* const* d_in, const int* in_sizes, int n_in,
                              void* d_out, int out_size, void* d_ws, size_t ws_size,
                              hipStream_t stream) {
  const float* x  = (const float*)d_in[0];
  const float* w1 = (const float*)d_in[1];
  const float* w2 = (const float*)d_in[2];
  const int*  tpe = (const int*)d_in[3];

  char* ws = (char*)d_ws;
  int4* map     = (int4*)ws;                       // up to 256 entries
  int*  nblocks = (int*)(ws + 4096);
  u16*  xb      = (u16*)(ws + 8192);               // T*H bf16 = 32MB
  u16*  hb      = xb + (size_t)TDIM * HDIM;        // T*F bf16 = 64MB

  k_prep<<<1, 64, 0, stream>>>(tpe, map, nblocks);
  k_conv<<<2048, 256, 0, stream>>>((const float4*)x, (uint2*)xb, (TDIM * HDIM) / 4);
  // max M-blocks at BM=256: sum ceil(n_e/256) <= 128
  // GEMM1: h = gelu(x @ w1^T)   B=w1 f32 [F][H] = [N][K], NY=16
  k_gemm<HDIM, FDIM, true,  1, 16><<<128 * 16, 512, 0, stream>>>(
      xb, w1, (void*)hb, map, nblocks);
  // GEMM2: out = h @ w2         B=w2 f32 [F][H] = [K][N], NY=8
  k_gemm<FDIM, HDIM, false, 2, 8><<<128 * 8, 512, 0, stream>>>(
      hb, w2, d_out, map, nblocks);
}

// Round 8
// 517.470 us; speedup vs baseline: 1.0828x; 1.0446x over previous
//
#include <hip/hip_runtime.h>
#include <hip/hip_bf16.h>

#define NE 64
#define HDIM 1024
#define FDIM 2048
#define TDIM 16384

typedef __attribute__((ext_vector_type(8))) short short8;
typedef __attribute__((ext_vector_type(4))) float f32x4;
typedef unsigned short u16;
typedef unsigned int u32;

struct IC0 { static constexpr int v = 0; };
struct IC1 { static constexpr int v = 1; };

__device__ __forceinline__ u16 f2bf(float f) {
  return __bfloat16_as_ushort(__float2bfloat16(f));
}
__device__ __forceinline__ u32 pk2(float a, float b) {
  return (u32)f2bf(a) | ((u32)f2bf(b) << 16);
}
template<int N> __device__ __forceinline__ void waitv() {
  if constexpr (N == 2)       asm volatile("s_waitcnt vmcnt(2)" ::: "memory");
  else if constexpr (N == 8)  asm volatile("s_waitcnt vmcnt(8)" ::: "memory");
}
__device__ __forceinline__ void waitl() {
  asm volatile("s_waitcnt lgkmcnt(0)" ::: "memory");
}

// ---- prep: build M-block map (expert, row0, rowend), BM=256 ----
__global__ void k_prep(const int* __restrict__ tpe, int4* __restrict__ map,
                       int* __restrict__ nblocks) {
  if (threadIdx.x != 0 || blockIdx.x != 0) return;
  int off = 0, nb = 0;
  for (int e = 0; e < NE; ++e) {
    int n = tpe[e];
    for (int r = 0; r < n; r += 256) {
      int re = (r + 256 < n) ? (r + 256) : n;
      map[nb++] = make_int4(e, off + r, off + re, 0);
    }
    off += n;
  }
  *nblocks = nb;
}

// ---- f32 -> bf16 convert ----
__global__ void k_conv(const float4* __restrict__ in, uint2* __restrict__ out, int n4) {
  int stride = gridDim.x * blockDim.x;
  for (int i = blockIdx.x * blockDim.x + threadIdx.x; i < n4; i += stride) {
    float4 v = in[i];
    uint2 o;
    o.x = pk2(v.x, v.y);
    o.y = pk2(v.z, v.w);
    out[i] = o;
  }
}

// ---- grouped GEMM: 256x128 tile, BK=32, 512 threads (8 waves of 64x64).
// Single s_barrier per K-step; counted vmcnt keeps loads in flight across it.
// ALL issues are UNCONDITIONAL (tail uses clamped dummy indices into the dead
// LDS buffer) so the in-flight vmem pattern is identical at every iteration:
//   top-of-body outstanding = B(t+1)[LB] A(t)[2] B(t+2)[LB]
//   -> s_waitcnt vmcnt(LB) drains B(t+1)+A(t), leaves B(t+2).   (tail-race fix)
// A: bf16, gload_lds into LDS dbuf, XOR-swizzled source chunk c^((r>>1)&3),
//    same XOR on frag read -> conflict-free ds_read_b128.
// B: f32 w, 2-iter reg flight (ping-pong sets), cvt+ds_write into LDS dbuf
//    (rows padded to 80B: conflict-free).
//   BMODE==1: B [N][K] k-contig  -> 2x float4/thread
//   BMODE==2: B [K][N] n-contig  -> 8x f32/thread (1 n-col x 8 k)
template<int K, int N, bool GELU, int BMODE, int NY>
__global__ __launch_bounds__(512) void k_gemm(
    const u16* __restrict__ A, const float* __restrict__ Bf, void* __restrict__ C,
    const int4* __restrict__ map, const int* __restrict__ nblocks)
{
  const int mblk = (int)blockIdx.x / NY;
  const int nblk = (int)blockIdx.x % NY;
  if (mblk >= *nblocks) return;
  const int4 mi = map[mblk];
  const int e = mi.x, row0 = mi.y, rowend = mi.z;
  const int n0 = nblk << 7;
  const int NT = K / 32;                      // 32 or 64, even
  constexpr int LB = (BMODE == 1) ? 2 : 8;    // B vmem ops per iter per thread

  __shared__ __align__(16) u16 sa[2][8192];     // A [256][32] (swizzled), dbuf
  __shared__ __align__(16) u16 sb[2][128 * 40]; // B [128 n][40], dbuf

  const int tid = threadIdx.x;
  const int wid = tid >> 6, lane = tid & 63;
  const int wr = wid >> 1, wc = wid & 1;      // 4 row-quads x 2 col-halves
  const int fr = lane & 15, fq = lane >> 4;

  f32x4 acc[4][4];
#pragma unroll
  for (int m = 0; m < 4; ++m)
#pragma unroll
    for (int n = 0; n < 4; ++n) acc[m][n] = (f32x4)0.f;

  const float* B = Bf + (size_t)e * ((size_t)N * K);

  float4 rb1[2][2];                 // BMODE1 ping-pong reg sets
  float  rb2[2][8];                 // BMODE2 ping-pong reg sets
  const int bn  = tid & 127;        // BMODE2: owned n-column
  const int oct = tid >> 7;         // BMODE2: k-octet (0..3)

  auto issueA = [&](int t, int buf) {   // buf passed explicitly (dummy-safe)
#pragma unroll
    for (int i = 0; i < 2; ++i) {
      int slot = i * 512 + tid;                 // row=slot>>2, chunk=slot&3
      int r = slot >> 2, c = slot & 3;
      int cs = c ^ ((r >> 1) & 3);              // pre-swizzled source chunk
      int row = row0 + r;
      row = row < TDIM ? row : TDIM - 1;
      const u16* g = A + (size_t)row * K + t * 32 + cs * 8;
      __builtin_amdgcn_global_load_lds(
          (const __attribute__((address_space(1))) u32*)g,
          (__attribute__((address_space(3))) u32*)(&sa[buf][i * 4096 + wid * 512]),
          16, 0, 0);
    }
  };
  auto loadB = [&](int t, auto ic) {
    constexpr int S = decltype(ic)::v;
    if constexpr (BMODE == 1) {
#pragma unroll
      for (int i = 0; i < 2; ++i) {
        int slot = i * 512 + tid;               // n=slot>>3, k16=slot&7
        rb1[S][i] = *(const float4*)(B + (size_t)(n0 + (slot >> 3)) * K + t * 32 + (slot & 7) * 4);
      }
    } else {
      const float* src = B + (size_t)(t * 32 + oct * 8) * N + n0 + bn;
#pragma unroll
      for (int i = 0; i < 8; ++i) rb2[S][i] = src[(size_t)i * N];
    }
  };
  auto writeB = [&](int buf, auto ic) {
    constexpr int S = decltype(ic)::v;
    if constexpr (BMODE == 1) {
#pragma unroll
      for (int i = 0; i < 2; ++i) {
        int slot = i * 512 + tid;
        uint2 o;
        o.x = pk2(rb1[S][i].x, rb1[S][i].y);
        o.y = pk2(rb1[S][i].z, rb1[S][i].w);
        *(uint2*)(&sb[buf][(slot >> 3) * 40 + (slot & 7) * 4]) = o;
      }
    } else {
      uint4 c;
      c.x = pk2(rb2[S][0], rb2[S][1]); c.y = pk2(rb2[S][2], rb2[S][3]);
      c.z = pk2(rb2[S][4], rb2[S][5]); c.w = pk2(rb2[S][6], rb2[S][7]);
      *(uint4*)(&sb[buf][bn * 40 + oct * 8]) = c;   // byte bn*80+oct*16 (80=5x16)
    }
  };

  auto body = [&](int t, auto icCur) {
    waitv<LB>();         // A(t) landed; B(t+1) regs complete; B(t+2) stays in flight
    waitl();             // own ds_writes from prev iter drained
    __builtin_amdgcn_s_barrier();   // ONE barrier per K-step
    const int cur = t & 1, nxt = cur ^ 1;
    short8 av[4], bv[4];
#pragma unroll
    for (int m = 0; m < 4; ++m) {
      const int row = wr * 64 + m * 16 + fr;
      av[m] = *(const short8*)(&sa[cur][row * 32 + (fq ^ ((row >> 1) & 3)) * 8]);
    }
#pragma unroll
    for (int n = 0; n < 4; ++n)
      bv[n] = *(const short8*)(&sb[cur][(wc * 64 + n * 16 + fr) * 40 + fq * 8]);
    // UNCONDITIONAL issues (clamped dummies at tail keep vmcnt pattern exact).
    issueA((t + 1 < NT) ? (t + 1) : (NT - 1), nxt);   // -> sa[nxt], dead buf if dummy
    writeB(nxt, icCur);                               // sb[nxt] <- B(t+1) regs
    loadB((t + 3 < NT) ? (t + 3) : (NT - 1), icCur);  // refill same reg set
#pragma unroll
    for (int m = 0; m < 4; ++m)
#pragma unroll
      for (int n = 0; n < 4; ++n)
        acc[m][n] = __builtin_amdgcn_mfma_f32_16x16x32_bf16(av[m], bv[n], acc[m][n], 0, 0, 0);
  };

  // prologue — reproduces steady-state in-flight ages
  issueA(0, 0);         // sa[0]
  loadB(0, IC0{});
  loadB(1, IC1{});
  waitv<LB>();          // drains A(0)+B(0); B(1) stays in flight
  writeB(0, IC0{});     // sb[0] <- B(0)
  loadB(2, IC0{});
  for (int t = 0; t < NT; t += 2) {
    body(t, IC1{});     // writes B(t+1) from set1, refills set1 with B(t+3)
    body(t + 1, IC0{});
  }

  // epilogue: C/D layout row=(lane>>4)*4+j, col=lane&15
#pragma unroll
  for (int m = 0; m < 4; ++m) {
    const int rb = row0 + wr * 64 + m * 16 + fq * 4;
#pragma unroll
    for (int n = 0; n < 4; ++n) {
      const int col = n0 + wc * 64 + n * 16 + fr;
#pragma unroll
      for (int j = 0; j < 4; ++j) {
        int r = rb + j;
        if (r < rowend) {
          float vv = acc[m][n][j];
          if constexpr (GELU) {
            vv = 0.5f * vv * (1.f + erff(vv * 0.70710678118654752f));
            ((u16*)C)[(size_t)r * N + col] = f2bf(vv);
          } else {
            ((float*)C)[(size_t)r * N + col] = vv;
          }
        }
      }
    }
  }
}

extern "C" void kernel_launch(void* const* d_in, const int* in_sizes, int n_in,
                              void* d_out, int out_size, void* d_ws, size_t ws_size,
                              hipStream_t stream) {
  const float* x  = (const float*)d_in[0];
  const float* w1 = (const float*)d_in[1];
  const float* w2 = (const float*)d_in[2];
  const int*  tpe = (const int*)d_in[3];

  char* ws = (char*)d_ws;
  int4* map     = (int4*)ws;                       // up to 256 entries
  int*  nblocks = (int*)(ws + 4096);
  u16*  xb      = (u16*)(ws + 8192);               // T*H bf16 = 32MB
  u16*  hb      = xb + (size_t)TDIM * HDIM;        // T*F bf16 = 64MB

  k_prep<<<1, 64, 0, stream>>>(tpe, map, nblocks);
  k_conv<<<2048, 256, 0, stream>>>((const float4*)x, (uint2*)xb, (TDIM * HDIM) / 4);
  // max M-blocks at BM=256: sum ceil(n_e/256) <= 128
  // GEMM1: h = gelu(x @ w1^T)   B=w1 f32 [F][H] = [N][K], NY=16
  k_gemm<HDIM, FDIM, true,  1, 16><<<128 * 16, 512, 0, stream>>>(
      xb, w1, (void*)hb, map, nblocks);
  // GEMM2: out = h @ w2         B=w2 f32 [F][H] = [K][N], NY=8
  k_gemm<FDIM, HDIM, false, 2, 8><<<128 * 8, 512, 0, stream>>>(
      hb, w2, d_out, map, nblocks);
}

// Round 9
// 470.700 us; speedup vs baseline: 1.1904x; 1.0994x over previous
//
#include <hip/hip_runtime.h>
#include <hip/hip_bf16.h>

#define NE 64
#define HDIM 1024
#define FDIM 2048
#define TDIM 16384

typedef __attribute__((ext_vector_type(8))) short short8;
typedef __attribute__((ext_vector_type(4))) float f32x4;
typedef unsigned short u16;
typedef unsigned int u32;

struct IC0 { static constexpr int v = 0; };
struct IC1 { static constexpr int v = 1; };
template<int W> struct WN { static constexpr int v = W; };

__device__ __forceinline__ u16 f2bf(float f) {
  return __bfloat16_as_ushort(__float2bfloat16(f));
}
__device__ __forceinline__ u32 pk2(float a, float b) {
  return (u32)f2bf(a) | ((u32)f2bf(b) << 16);
}
template<int N> __device__ __forceinline__ void waitv() {
  if constexpr (N == 2)       asm volatile("s_waitcnt vmcnt(2)" ::: "memory");
  else if constexpr (N == 4)  asm volatile("s_waitcnt vmcnt(4)" ::: "memory");
  else if constexpr (N == 8)  asm volatile("s_waitcnt vmcnt(8)" ::: "memory");
  else if constexpr (N == 10) asm volatile("s_waitcnt vmcnt(10)" ::: "memory");
}
__device__ __forceinline__ void waitl() {
  asm volatile("s_waitcnt lgkmcnt(0)" ::: "memory");
}

// ---- prep: build M-block map (expert, row0, rowend), BM=256 ----
__global__ void k_prep(const int* __restrict__ tpe, int4* __restrict__ map,
                       int* __restrict__ nblocks) {
  if (threadIdx.x != 0 || blockIdx.x != 0) return;
  int off = 0, nb = 0;
  for (int e = 0; e < NE; ++e) {
    int n = tpe[e];
    for (int r = 0; r < n; r += 256) {
      int re = (r + 256 < n) ? (r + 256) : n;
      map[nb++] = make_int4(e, off + r, off + re, 0);
    }
    off += n;
  }
  *nblocks = nb;
}

// ---- f32 -> bf16 convert ----
__global__ void k_conv(const float4* __restrict__ in, uint2* __restrict__ out, int n4) {
  int stride = gridDim.x * blockDim.x;
  for (int i = blockIdx.x * blockDim.x + threadIdx.x; i < n4; i += stride) {
    float4 v = in[i];
    uint2 o;
    o.x = pk2(v.x, v.y);
    o.y = pk2(v.z, v.w);
    out[i] = o;
  }
}

// ---- grouped GEMM: 256x128 tile, BK=32, 512 threads (8 waves of 64x64).
// ONE s_barrier per K-step; counted vmcnt keeps loads in flight across it.
// A: bf16, gload_lds, 3-deep LDS rotation -> TRUE 2-body flight
//    (body(t) reads sa[t%3], issues A(t+2) into sa[(t+2)%3] — never a buffer
//    read this or next body). XOR-swizzled source chunk c^((r>>1)&3), same
//    XOR on frag read -> conflict-free ds_read_b128.
// B: f32 w, 2-body reg flight (ping-pong sets, static idx), cvt+ds_write into
//    LDS dbuf (80B rows: conflict-free).
// Steady top-of-body(t) outstanding, age order:
//   A(t)[2], B(t+1)[LB], A(t+1)[2], B(t+2)[LB]
//   -> vmcnt(2+LB) drains exactly A(t)+B(t+1).  body(0) peeled: vmcnt(LB)
//   (drains A(1) early — harmless).  Tail: unconditional clamped dummy issues
//   keep the in-flight pattern invariant (round-7 race fix).
//   BMODE==1: B [N][K] k-contig  -> 2x float4/thread   (LB=2)
//   BMODE==2: B [K][N] n-contig  -> 8x f32/thread      (LB=8)
template<int K, int N, bool GELU, int BMODE, int NY>
__global__ __launch_bounds__(512) void k_gemm(
    const u16* __restrict__ A, const float* __restrict__ Bf, void* __restrict__ C,
    const int4* __restrict__ map, const int* __restrict__ nblocks)
{
  const int mblk = (int)blockIdx.x / NY;
  const int nblk = (int)blockIdx.x % NY;
  if (mblk >= *nblocks) return;
  const int4 mi = map[mblk];
  const int e = mi.x, row0 = mi.y, rowend = mi.z;
  const int n0 = nblk << 7;
  const int NT = K / 32;                      // 32 or 64, even
  constexpr int LB = (BMODE == 1) ? 2 : 8;    // B vmem ops per body per thread

  __shared__ __align__(16) u16 sa[3][8192];     // A [256][32] (swizzled), 3-rot
  __shared__ __align__(16) u16 sb[2][128 * 40]; // B [128 n][40], dbuf

  const int tid = threadIdx.x;
  const int wid = tid >> 6, lane = tid & 63;
  const int wr = wid >> 1, wc = wid & 1;      // 4 row-quads x 2 col-halves
  const int fr = lane & 15, fq = lane >> 4;

  f32x4 acc[4][4];
#pragma unroll
  for (int m = 0; m < 4; ++m)
#pragma unroll
    for (int n = 0; n < 4; ++n) acc[m][n] = (f32x4)0.f;

  const float* B = Bf + (size_t)e * ((size_t)N * K);

  float4 rb1[2][2];                 // BMODE1 ping-pong reg sets
  float  rb2[2][8];                 // BMODE2 ping-pong reg sets
  const int bn  = tid & 127;        // BMODE2: owned n-column
  const int oct = tid >> 7;         // BMODE2: k-octet (0..3)

  auto issueA = [&](int t, int buf) {
#pragma unroll
    for (int i = 0; i < 2; ++i) {
      int slot = i * 512 + tid;                 // row=slot>>2, chunk=slot&3
      int r = slot >> 2, c = slot & 3;
      int cs = c ^ ((r >> 1) & 3);              // pre-swizzled source chunk
      int row = row0 + r;
      row = row < TDIM ? row : TDIM - 1;
      const u16* g = A + (size_t)row * K + t * 32 + cs * 8;
      __builtin_amdgcn_global_load_lds(
          (const __attribute__((address_space(1))) u32*)g,
          (__attribute__((address_space(3))) u32*)(&sa[buf][i * 4096 + wid * 512]),
          16, 0, 0);
    }
  };
  auto loadB = [&](int t, auto ic) {
    constexpr int S = decltype(ic)::v;
    if constexpr (BMODE == 1) {
#pragma unroll
      for (int i = 0; i < 2; ++i) {
        int slot = i * 512 + tid;               // n=slot>>3, k16=slot&7
        rb1[S][i] = *(const float4*)(B + (size_t)(n0 + (slot >> 3)) * K + t * 32 + (slot & 7) * 4);
      }
    } else {
      const float* src = B + (size_t)(t * 32 + oct * 8) * N + n0 + bn;
#pragma unroll
      for (int i = 0; i < 8; ++i) rb2[S][i] = src[(size_t)i * N];
    }
  };
  auto writeB = [&](int buf, auto ic) {
    constexpr int S = decltype(ic)::v;
    if constexpr (BMODE == 1) {
#pragma unroll
      for (int i = 0; i < 2; ++i) {
        int slot = i * 512 + tid;
        uint2 o;
        o.x = pk2(rb1[S][i].x, rb1[S][i].y);
        o.y = pk2(rb1[S][i].z, rb1[S][i].w);
        *(uint2*)(&sb[buf][(slot >> 3) * 40 + (slot & 7) * 4]) = o;
      }
    } else {
      uint4 c;
      c.x = pk2(rb2[S][0], rb2[S][1]); c.y = pk2(rb2[S][2], rb2[S][3]);
      c.z = pk2(rb2[S][4], rb2[S][5]); c.w = pk2(rb2[S][6], rb2[S][7]);
      *(uint4*)(&sb[buf][bn * 40 + oct * 8]) = c;   // byte bn*80+oct*16 (80=5x16)
    }
  };

  auto body = [&](int t, auto icCur, auto wn) {
    waitv<decltype(wn)::v>();  // steady: drains A(t)+B(t+1)
    waitl();                   // own ds_writes from prev body drained
    __builtin_amdgcn_s_barrier();
    const int cur3 = t % 3, curb = t & 1, nxtb = curb ^ 1;
    short8 av[4], bv[4];
#pragma unroll
    for (int m = 0; m < 4; ++m) {
      const int row = wr * 64 + m * 16 + fr;
      av[m] = *(const short8*)(&sa[cur3][row * 32 + (fq ^ ((row >> 1) & 3)) * 8]);
    }
#pragma unroll
    for (int n = 0; n < 4; ++n)
      bv[n] = *(const short8*)(&sb[curb][(wc * 64 + n * 16 + fr) * 40 + fq * 8]);
    // UNCONDITIONAL issues; tile index clamped at tail, buffers keep rotating.
    issueA((t + 2 < NT) ? (t + 2) : (NT - 1), (t + 2) % 3);
    writeB(nxtb, icCur);                               // sb[nxt] <- B(t+1) regs
    loadB((t + 3 < NT) ? (t + 3) : (NT - 1), icCur);   // refill same reg set
#pragma unroll
    for (int m = 0; m < 4; ++m)
#pragma unroll
      for (int n = 0; n < 4; ++n)
        acc[m][n] = __builtin_amdgcn_mfma_f32_16x16x32_bf16(av[m], bv[n], acc[m][n], 0, 0, 0);
  };

  // prologue (order matters for vmcnt age accounting):
  issueA(0, 0);         // A(0) -> sa[0]
  loadB(0, IC0{});      // B(0) -> set0
  issueA(1, 1);         // A(1) -> sa[1]
  loadB(1, IC1{});      // B(1) -> set1
  waitv<2 + LB>();      // drains A(0)+B(0); leaves A(1),B(1)
  writeB(0, IC0{});     // sb[0] <- B(0)
  loadB(2, IC0{});      // B(2) -> set0
  // outstanding: A(1)[2], B(1)[LB], B(2)[LB]

  body(0, IC1{}, WN<LB>{});       // drains A(1)(early)+B(1); leaves B(2)
  body(1, IC0{}, WN<2 + LB>{});   // drains B(2); leaves A(2),B(3)
  for (int t = 2; t < NT; t += 2) {
    body(t,     IC1{}, WN<2 + LB>{});
    body(t + 1, IC0{}, WN<2 + LB>{});
  }

  // epilogue: C/D layout row=(lane>>4)*4+j, col=lane&15
#pragma unroll
  for (int m = 0; m < 4; ++m) {
    const int rb = row0 + wr * 64 + m * 16 + fq * 4;
#pragma unroll
    for (int n = 0; n < 4; ++n) {
      const int col = n0 + wc * 64 + n * 16 + fr;
#pragma unroll
      for (int j = 0; j < 4; ++j) {
        int r = rb + j;
        if (r < rowend) {
          float vv = acc[m][n][j];
          if constexpr (GELU) {
            vv = 0.5f * vv * (1.f + erff(vv * 0.70710678118654752f));
            ((u16*)C)[(size_t)r * N + col] = f2bf(vv);
          } else {
            ((float*)C)[(size_t)r * N + col] = vv;
          }
        }
      }
    }
  }
}

extern "C" void kernel_launch(void* const* d_in, const int* in_sizes, int n_in,
                              void* d_out, int out_size, void* d_ws, size_t ws_size,
                              hipStream_t stream) {
  const float* x  = (const float*)d_in[0];
  const float* w1 = (const float*)d_in[1];
  const float* w2 = (const float*)d_in[2];
  const int*  tpe = (const int*)d_in[3];

  char* ws = (char*)d_ws;
  int4* map     = (int4*)ws;                       // up to 256 entries
  int*  nblocks = (int*)(ws + 4096);
  u16*  xb      = (u16*)(ws + 8192);               // T*H bf16 = 32MB
  u16*  hb      = xb + (size_t)TDIM * HDIM;        // T*F bf16 = 64MB

  k_prep<<<1, 64, 0, stream>>>(tpe, map, nblocks);
  k_conv<<<2048, 256, 0, stream>>>((const float4*)x, (uint2*)xb, (TDIM * HDIM) / 4);
  // GEMM1: h = gelu(x @ w1^T)   B=w1 f32 [F][H] = [N][K], NY=16
  k_gemm<HDIM, FDIM, true,  1, 16><<<128 * 16, 512, 0, stream>>>(
      xb, w1, (void*)hb, map, nblocks);
  // GEMM2: out = h @ w2         B=w2 f32 [F][H] = [K][N], NY=8
  k_gemm<FDIM, HDIM, false, 2, 8><<<128 * 8, 512, 0, stream>>>(
      hb, w2, d_out, map, nblocks);
}